// Round 5
// baseline (152.994 us; speedup 1.0000x reference)
//
#include <hip/hip_runtime.h>
#include <math.h>

#define BB 4
#define SS 1024
#define XX 1024
#define CC 8
#define DD 2
#define WIDTH 16
#define DEPTH 4

#define NLUT 4096
#define RSCALE 16.0f          // grid spacing 1/16, domain [0, 256)
#define GQ 8                  // queries per block
#define NBUILD 64             // builder blocks; 64 LUT entries each (one per lane)
#define MAGIC 0x5ca1ab1e

// tanh(v) = copysign(2/(1+exp(-2|v|)) - 1, v)
__device__ __forceinline__ float fast_tanh(float v) {
    float ax = __builtin_fabsf(v);
    float e  = __builtin_amdgcn_exp2f(ax * -2.885390081777927f); // exp(-2|v|)
    float t  = fmaf(2.0f, __builtin_amdgcn_rcpf(1.0f + e), -1.0f);
    return __builtin_copysignf(t, v);
}

// Fused: build f(r) LUT (64 blocks), flag-sync, then per-block 8-query conv.
__global__ __launch_bounds__(256) void ccl_fused(
    const float* __restrict__ yu,     // (B,S,C+D)
    const float* __restrict__ x,      // (B,X,D)
    const float* __restrict__ W_in, const float* __restrict__ b_in,
    const float* __restrict__ W_hid, const float* __restrict__ b_hid,
    const float* __restrict__ W_out, const float* __restrict__ b_out,
    float* __restrict__ lut_g,        // ws[0 .. NLUT)
    int*   __restrict__ flags,        // ws[NLUT .. NLUT+NBUILD)
    float* __restrict__ out)          // (B,X,C)
{
    __shared__ float lut_s[NLUT];     // 16 KB
    __shared__ float red[4][CC];

    const int bx   = blockIdx.x;
    const int b    = bx / (XX / GQ);            // 512 blocks: 128 per batch
    const int xi0  = (bx % (XX / GQ)) * GQ;
    const int tid  = threadIdx.x;
    const int lane = tid & 63;
    const int wv   = tid >> 6;

    // ---- prefetch this thread's 4 s-points into registers (before any L2 inv) ----
    const float* yub = yu + (size_t)b * SS * (CC + DD);
    float2 yp[4];
    float  up[4][CC];
#pragma unroll
    for (int i = 0; i < 4; ++i) {
        const int s = tid + i * 256;
        const float2* row = reinterpret_cast<const float2*>(yub + (size_t)s * (CC + DD));
        float2 a0 = row[0], a1 = row[1], a2 = row[2], a3 = row[3];
        yp[i] = row[4];
        up[i][0] = a0.x; up[i][1] = a0.y; up[i][2] = a1.x; up[i][3] = a1.y;
        up[i][4] = a2.x; up[i][5] = a2.y; up[i][6] = a3.x; up[i][7] = a3.y;
    }
    // query coords (block-uniform)
    float qx[GQ], qy[GQ];
    {
        const float* xp = x + ((size_t)b * XX + xi0) * DD;
#pragma unroll
        for (int q = 0; q < GQ; ++q) { qx[q] = xp[2 * q]; qy[q] = xp[2 * q + 1]; }
    }

    // ---- build phase: blocks 0..63, wave 0, one LUT entry per lane ----
    if (bx < NBUILD && wv == 0) {
        const int idx = bx * 64 + lane;
        const float r = (float)idx * (1.0f / RSCALE);

        float h[WIDTH];
#pragma unroll
        for (int j = 0; j < WIDTH; ++j) h[j] = fmaf(r, W_in[j], b_in[j]);
#pragma unroll
        for (int l = 0; l < DEPTH; ++l) {
            const float* W  = W_hid + l * WIDTH * WIDTH;
            const float* bb = b_hid + l * WIDTH;
            float pre[WIDTH];
#pragma unroll
            for (int j = 0; j < WIDTH; ++j) pre[j] = bb[j];
#pragma unroll
            for (int i = 0; i < WIDTH; ++i) {
                const float hi = h[i];
#pragma unroll
                for (int j = 0; j < WIDTH; ++j)
                    pre[j] = fmaf(hi, W[i * WIDTH + j], pre[j]);
            }
#pragma unroll
            for (int j = 0; j < WIDTH; ++j) h[j] += fast_tanh(pre[j]);
        }
        float k = b_out[0];
#pragma unroll
        for (int j = 0; j < WIDTH; ++j) k = fmaf(h[j], W_out[j], k);

        lut_g[idx] = k;                       // 64-lane store (one instruction)
        if (lane == 0)                        // release waits on the wave's vmem
            __hip_atomic_store(&flags[bx], MAGIC, __ATOMIC_RELEASE,
                               __HIP_MEMORY_SCOPE_AGENT);
    }

    // ---- sync phase: wave 0 of every block acquire-polls all 64 flags ----
    if (wv == 0) {
        for (;;) {
            int v = __hip_atomic_load(&flags[lane], __ATOMIC_ACQUIRE,
                                      __HIP_MEMORY_SCOPE_AGENT);
            if (__all(v == MAGIC)) break;
            __builtin_amdgcn_s_sleep(2);
        }
    }
    __syncthreads();

    // ---- stage LUT to LDS: 4 float4 per thread ----
    {
        const float4* src = reinterpret_cast<const float4*>(lut_g);
        float4*       dst = reinterpret_cast<float4*>(lut_s);
#pragma unroll
        for (int i = 0; i < NLUT / 4 / 256; ++i)
            dst[tid + i * 256] = src[tid + i * 256];
    }
    __syncthreads();

    // ---- main compute: 8 queries against this thread's 4 pinned points ----
#pragma unroll
    for (int q = 0; q < GQ; ++q) {
        float acc[CC];
#pragma unroll
        for (int c = 0; c < CC; ++c) acc[c] = 0.0f;

#pragma unroll
        for (int i = 0; i < 4; ++i) {
            const float d0 = qx[q] - yp[i].x;
            const float d1 = qy[q] - yp[i].y;
            const float r  = fmaf(d0, d0, d1 * d1);

            float rf = r * RSCALE;
            int   ix = (int)rf;
            ix = min(ix, NLUT - 2);
            const float w  = rf - (float)ix;
            const float f0 = lut_s[ix];
            const float f1 = lut_s[ix + 1];
            const float k  = fmaf(w, f1 - f0, f0);

#pragma unroll
            for (int c = 0; c < CC; ++c) acc[c] = fmaf(k, up[i][c], acc[c]);
        }

#pragma unroll
        for (int c = 0; c < CC; ++c) {
            float v = acc[c];
#pragma unroll
            for (int off = 32; off > 0; off >>= 1)
                v += __shfl_down(v, off, 64);
            acc[c] = v;
        }

        __syncthreads();
        if (lane == 0) {
#pragma unroll
            for (int c = 0; c < CC; ++c) red[wv][c] = acc[c];
        }
        __syncthreads();
        if (tid < CC) {
            const float v = red[0][tid] + red[1][tid] + red[2][tid] + red[3][tid];
            out[((size_t)b * XX + xi0 + q) * CC + tid] = v * (1.0f / SS);
        }
    }
}

extern "C" void kernel_launch(void* const* d_in, const int* in_sizes, int n_in,
                              void* d_out, int out_size, void* d_ws, size_t ws_size,
                              hipStream_t stream) {
    const float* yu    = (const float*)d_in[0];
    const float* x     = (const float*)d_in[1];
    const float* W_in  = (const float*)d_in[2];
    const float* b_in  = (const float*)d_in[3];
    const float* W_hid = (const float*)d_in[4];
    const float* b_hid = (const float*)d_in[5];
    const float* W_out = (const float*)d_in[6];
    const float* b_out = (const float*)d_in[7];
    float* out   = (float*)d_out;
    float* lut   = (float*)d_ws;
    int*   flags = (int*)d_ws + NLUT;

    ccl_fused<<<dim3(BB * XX / GQ), dim3(256), 0, stream>>>(
        yu, x, W_in, b_in, W_hid, b_hid, W_out, b_out, lut, flags, out);
}

// Round 6
// 84.170 us; speedup vs baseline: 1.8177x; 1.8177x over previous
//
#include <hip/hip_runtime.h>
#include <math.h>

#define BB 4
#define SS 1024
#define XX 1024
#define CC 8
#define DD 2
#define WIDTH 16
#define DEPTH 4

#define NLUT 4096
#define RSCALE 16.0f          // grid spacing 1/16, domain [0, 256)
#define GQ 8                  // queries per block

// tanh(v) = copysign(2/(1+exp(-2|v|)) - 1, v)
__device__ __forceinline__ float fast_tanh(float v) {
    float ax = __builtin_fabsf(v);
    float e  = __builtin_amdgcn_exp2f(ax * -2.885390081777927f); // exp(-2|v|)
    float t  = fmaf(2.0f, __builtin_amdgcn_rcpf(1.0f + e), -1.0f);
    return __builtin_copysignf(t, v);
}

// ---- kernel 1: tabulate k = f(r); 64 blocks x 64 threads, one entry/thread ----
__global__ __launch_bounds__(64) void build_lut(
    const float* __restrict__ W_in, const float* __restrict__ b_in,
    const float* __restrict__ W_hid, const float* __restrict__ b_hid,
    const float* __restrict__ W_out, const float* __restrict__ b_out,
    float* __restrict__ lut)
{
    const int idx = blockIdx.x * 64 + threadIdx.x;   // 4096 total
    const float r = (float)idx * (1.0f / RSCALE);

    float h[WIDTH];
#pragma unroll
    for (int j = 0; j < WIDTH; ++j) h[j] = fmaf(r, W_in[j], b_in[j]);

#pragma unroll
    for (int l = 0; l < DEPTH; ++l) {
        const float* W  = W_hid + l * WIDTH * WIDTH;
        const float* bb = b_hid + l * WIDTH;
        float pre[WIDTH];
#pragma unroll
        for (int j = 0; j < WIDTH; ++j) pre[j] = bb[j];
#pragma unroll
        for (int i = 0; i < WIDTH; ++i) {
            const float hi = h[i];
#pragma unroll
            for (int j = 0; j < WIDTH; ++j)
                pre[j] = fmaf(hi, W[i * WIDTH + j], pre[j]);
        }
#pragma unroll
        for (int j = 0; j < WIDTH; ++j) h[j] += fast_tanh(pre[j]);
    }

    float k = b_out[0];
#pragma unroll
    for (int j = 0; j < WIDTH; ++j) k = fmaf(h[j], W_out[j], k);
    lut[idx] = k;
}

// ---- kernel 2: block = 8 query points; yu rows pinned in registers ----
__global__ __launch_bounds__(256) void ccl_main(
    const float* __restrict__ yu,     // (B,S,C+D)
    const float* __restrict__ x,      // (B,X,D)
    const float* __restrict__ lut_g,  // (NLUT)
    float* __restrict__ out)          // (B,X,C)
{
    __shared__ float lut_s[NLUT];     // 16 KB
    __shared__ float red[GQ * 4 * CC];// 1 KB: [q][wave][ch]

    const int bx   = blockIdx.x;
    const int b    = bx / (XX / GQ);          // 512 blocks: 128 per batch
    const int xi0  = (bx % (XX / GQ)) * GQ;
    const int tid  = threadIdx.x;
    const int lane = tid & 63;
    const int wv   = tid >> 6;

    // stage LUT: 4 float4 per thread (coalesced)
    {
        const float4* src = reinterpret_cast<const float4*>(lut_g);
        float4*       dst = reinterpret_cast<float4*>(lut_s);
#pragma unroll
        for (int i = 0; i < NLUT / 4 / 256; ++i)
            dst[tid + i * 256] = src[tid + i * 256];
    }

    // pin this thread's 4 s-points (y and u) in registers
    const float* yub = yu + (size_t)b * SS * (CC + DD);
    float2 yp[4];
    float  up[4][CC];
#pragma unroll
    for (int i = 0; i < 4; ++i) {
        const int s = tid + i * 256;
        const float2* row = reinterpret_cast<const float2*>(yub + (size_t)s * (CC + DD));
        float2 a0 = row[0], a1 = row[1], a2 = row[2], a3 = row[3];
        yp[i] = row[4];
        up[i][0] = a0.x; up[i][1] = a0.y; up[i][2] = a1.x; up[i][3] = a1.y;
        up[i][4] = a2.x; up[i][5] = a2.y; up[i][6] = a3.x; up[i][7] = a3.y;
    }

    // query coords (block-uniform)
    float qx[GQ], qy[GQ];
    {
        const float* xp = x + ((size_t)b * XX + xi0) * DD;
#pragma unroll
        for (int q = 0; q < GQ; ++q) { qx[q] = xp[2 * q]; qy[q] = xp[2 * q + 1]; }
    }

    __syncthreads();

    const bool b0 = (lane & 1) != 0;
    const bool b1 = (lane & 2) != 0;
    const bool b2 = (lane & 4) != 0;

    float vq[GQ];   // per-query: full-wave sum of channel (lane&7)

#pragma unroll
    for (int q = 0; q < GQ; ++q) {
        float acc[CC];
#pragma unroll
        for (int c = 0; c < CC; ++c) acc[c] = 0.0f;

#pragma unroll
        for (int i = 0; i < 4; ++i) {
            const float d0 = qx[q] - yp[i].x;
            const float d1 = qy[q] - yp[i].y;
            const float r  = fmaf(d0, d0, d1 * d1);

            float rf = r * RSCALE;
            int   ix = (int)rf;
            ix = min(ix, NLUT - 2);
            const float w  = rf - (float)ix;
            const float f0 = lut_s[ix];
            const float f1 = lut_s[ix + 1];
            const float k  = fmaf(w, f1 - f0, f0);

#pragma unroll
            for (int c = 0; c < CC; ++c) acc[c] = fmaf(k, up[i][c], acc[c]);
        }

        // merging butterfly: 8 channels -> 1 value/lane (channel = lane&7)
        float m[4];
#pragma unroll
        for (int i = 0; i < 4; ++i) {            // xor 1: keep ch 2i+b0
            float u = b0 ? acc[2 * i + 1] : acc[2 * i];
            float w = b0 ? acc[2 * i]     : acc[2 * i + 1];
            m[i] = u + __shfl_xor(w, 1, 64);
        }
        float n[2];
#pragma unroll
        for (int j = 0; j < 2; ++j) {            // xor 2: keep 4j+2b1+b0
            float u = b1 ? m[2 * j + 1] : m[2 * j];
            float w = b1 ? m[2 * j]     : m[2 * j + 1];
            n[j] = u + __shfl_xor(w, 2, 64);
        }
        {                                        // xor 4: keep 4b2+2b1+b0 = lane&7
            float u = b2 ? n[1] : n[0];
            float w = b2 ? n[0] : n[1];
            float p = u + __shfl_xor(w, 4, 64);
            p += __shfl_xor(p, 8, 64);
            p += __shfl_xor(p, 16, 64);
            p += __shfl_xor(p, 32, 64);
            vq[q] = p;
        }
    }

    // single epilogue: lanes 0..7 of each wave publish, then 64 threads store
    if (lane < CC) {
#pragma unroll
        for (int q = 0; q < GQ; ++q)
            red[(q * 4 + wv) * CC + lane] = vq[q];
    }
    __syncthreads();
    if (tid < GQ * CC) {
        const int q = tid >> 3;
        const int c = tid & 7;
        const float v = red[(q * 4 + 0) * CC + c] + red[(q * 4 + 1) * CC + c] +
                        red[(q * 4 + 2) * CC + c] + red[(q * 4 + 3) * CC + c];
        out[((size_t)b * XX + xi0 + q) * CC + c] = v * (1.0f / SS);
    }
}

extern "C" void kernel_launch(void* const* d_in, const int* in_sizes, int n_in,
                              void* d_out, int out_size, void* d_ws, size_t ws_size,
                              hipStream_t stream) {
    const float* yu    = (const float*)d_in[0];
    const float* x     = (const float*)d_in[1];
    const float* W_in  = (const float*)d_in[2];
    const float* b_in  = (const float*)d_in[3];
    const float* W_hid = (const float*)d_in[4];
    const float* b_hid = (const float*)d_in[5];
    const float* W_out = (const float*)d_in[6];
    const float* b_out = (const float*)d_in[7];
    float* out = (float*)d_out;
    float* lut = (float*)d_ws;        // 16 KB of scratch

    build_lut<<<dim3(NLUT / 64), dim3(64), 0, stream>>>(
        W_in, b_in, W_hid, b_hid, W_out, b_out, lut);

    ccl_main<<<dim3(BB * XX / GQ), dim3(256), 0, stream>>>(yu, x, lut, out);
}